// Round 1
// baseline (181.396 us; speedup 1.0000x reference)
//
#include <hip/hip_runtime.h>
#include <hip/hip_cooperative_groups.h>

namespace cg = cooperative_groups;

// HDDTBinaryLoss: loss = mean((t - sigmoid(x))^2 * dist), dist = sum of 4
// exact squared EDTs (p>0.5, ~p, t>0.5, ~t), B=8, C=1, H=W=256.
//
// Round 4 structure: SINGLE cooperative kernel (512 blocks x 256 threads).
//  Phase 1 (all 512 blocks): column occupancy bitmasks as 8-bit partials.
//     PM u8[ ((((src*8+b)*4+wd)*256 + w)*4 + q)*2 + half ] -- little-endian,
//     so the 8 q/half-partials alias to the same u64 word (bit h = row
//     wd*64+h, col w) that phase 2 reads. 128 KiB of d_ws.
//  grid.sync() (cooperative) replaces the old kernel boundary; __threadfence
//     provides the device-scope release so phase-1 L2 lines are visible
//     cross-XCD in phase 2.
//  Phase 2 (identical math to R3 envelope, block = (b, 4 rows)):
//     - stage g2[row][k][4 masks] in LDS from bitmasks (clz/ffs 1-D EDT,
//       sentinels reproduce ref BIG=512 carry exactly; absmax 0.0 in R2/R3).
//     - EXACT adaptive envelope: dt2[j] = min_k (j-k)^2 + g2[k]. Window
//       |kk|<=2 (includes kk=0 => own-column g2, hard upper bound U), then
//       R = floor(sqrt(U))+1 wave-maxed -> uniform loop kk=3..R. Pruned kk
//       have kk^2 >= U so they provably cannot improve the min -> exact for
//       ANY input; random 50/50 masks give R ~ 3-6.
//     - weight by (t-p)^2, block-reduce, atomicAdd into d_out.

#define IMG 65536

// Squared 1-D column EDT at row i from the mask's ZERO-set bits (z word w
// covers rows 64w..64w+63; bit set = pixel is False for the mask).
__device__ __forceinline__ float g2_from_words(unsigned long long z0,
                                               unsigned long long z1,
                                               unsigned long long z2,
                                               unsigned long long z3,
                                               int i) {
    int wi = i >> 6, bi = i & 63;
    unsigned long long lowm  = (~0ULL) >> (63 - bi);  // bits 0..bi
    unsigned long long highm = (~0ULL) << bi;         // bits bi..63
    unsigned long long z[4] = {z0, z1, z2, z3};

    int lz = -513;  // no zero above => fwd = i + 513  (ref: BIG + i + 1)
    #pragma unroll
    for (int w = 0; w < 4; ++w) {
        unsigned long long m = z[w];
        if (w == wi) m &= lowm;
        if (w >  wi) m = 0;
        if (m) lz = (w << 6) + 63 - __clzll(m);
    }
    int fz = 768;   // no zero below => bwd = 768 - i  (ref: BIG + (255-i) + 1)
    #pragma unroll
    for (int w = 3; w >= 0; --w) {
        unsigned long long m = z[w];
        if (w == wi) m &= highm;
        if (w <  wi) m = 0;
        if (m) fz = (w << 6) + (__ffsll(m) - 1);
    }
    int u = i - lz, d = fz - i;
    float g = (float)(u < d ? u : d);
    return g * g;
}

__global__ __launch_bounds__(256) void hddt_fused(const float* __restrict__ inp,
                                                  const int* __restrict__ tgt,
                                                  unsigned char* PM,          // aliases BM (d_ws)
                                                  const unsigned long long* BM,
                                                  float* __restrict__ out) {
    __shared__ float4 sg2[4][256];   // [row in tile][k] = g2 of 4 masks
    __shared__ float wsum[4];

    // ---- phase 1: build column bitmasks; 512 blocks x 8 rows per thread ----
    {
        int bid = blockIdx.x;
        int w   = threadIdx.x;  // column
        if (bid == 0 && w == 0)   // d_out is poisoned before every replay
            __hip_atomic_store(out, 0.0f, __ATOMIC_RELAXED, __HIP_MEMORY_SCOPE_AGENT);

        int task = bid >> 1;    // 256 tasks: src=task>>7, b=(task>>4)&7, wd=(task>>2)&3, q=task&3
        int half = bid & 1;     // low/high 8 rows of the 16-row q-window
        int src  = task >> 7;
        int b    = (task >> 4) & 7;
        int wd   = (task >> 2) & 3;
        int q    = task & 3;
        int h0   = (wd << 6) + (q << 4) + (half << 3);
        int base = b * IMG + (h0 << 8) + w;

        unsigned int word = 0;
        if (src == 0) {
            #pragma unroll
            for (int hh = 0; hh < 8; ++hh)           // sigmoid(x)>0.5 <=> x>0
                word |= ((unsigned int)(inp[base + (hh << 8)] > 0.0f)) << hh;
        } else {
            #pragma unroll
            for (int hh = 0; hh < 8; ++hh)
                word |= ((unsigned int)(tgt[base + (hh << 8)] > 0)) << hh;
        }
        // byte (q*2+half) of the u64 word for (src,b,wd,w): bit h = row wd*64+q*16+half*8+hh
        PM[(((((size_t)src * 8 + b) * 4 + wd) * 256 + w) * 4 + q) * 2 + half] =
            (unsigned char)word;
    }

    __threadfence();          // device-scope release: make byte-stores visible cross-XCD
    cg::this_grid().sync();   // replaces the old K1->K2 kernel boundary

    // ---- phase 2: adaptive exact lower envelope (identical to R3) ----
    int b  = blockIdx.x >> 6;        // 512 blocks: 8 b x 64 row-tiles
    int r0 = (blockIdx.x & 63) << 2;
    int t  = threadIdx.x;

    // stage g2 from bitmasks: thread t = column t, all 4 rows
    {
        unsigned long long bp[4], bt[4];
        #pragma unroll
        for (int wd = 0; wd < 4; ++wd) {
            bp[wd] = BM[(((size_t)0 * 8 + b) * 4 + wd) * 256 + t];
            bt[wd] = BM[(((size_t)1 * 8 + b) * 4 + wd) * 256 + t];
        }
        #pragma unroll
        for (int rr = 0; rr < 4; ++rr) {
            int i = r0 + rr;
            float g0 = g2_from_words(~bp[0], ~bp[1], ~bp[2], ~bp[3], i); // p-mask
            float g1 = g2_from_words( bp[0],  bp[1],  bp[2],  bp[3], i); // ~p
            float g2 = g2_from_words(~bt[0], ~bt[1], ~bt[2], ~bt[3], i); // t-mask
            float g3 = g2_from_words( bt[0],  bt[1],  bt[2],  bt[3], i); // ~t
            sg2[rr][t] = make_float4(g0, g1, g2, g3);
        }
    }
    __syncthreads();

    // adaptive exact lower envelope: wave r = row r0+r, lane j0, 4 pixels
    int r  = t >> 6;
    int j0 = t & 63;
    float a[4][4];                   // [mask][q]
    #pragma unroll
    for (int m = 0; m < 4; ++m)
        #pragma unroll
        for (int q = 0; q < 4; ++q) a[m][q] = 1e30f;

    // window |kk| <= 2 (includes kk=0: own-column g2 -> hard upper bound)
    #pragma unroll
    for (int kk = -2; kk <= 2; ++kk) {
        float s = (float)(kk * kk);
        #pragma unroll
        for (int q = 0; q < 4; ++q) {
            int k = j0 + (q << 6) + kk;
            k = min(max(k, 0), 255);                 // clamped k is a valid candidate
            float4 g = sg2[r][k];                    // stride-1 ds_read_b128
            a[0][q] = fminf(a[0][q], g.x + s);
            a[1][q] = fminf(a[1][q], g.y + s);
            a[2][q] = fminf(a[2][q], g.z + s);
            a[3][q] = fminf(a[3][q], g.w + s);
        }
    }

    // prune radius: kk^2 >= U can't improve any entry of this lane
    float U = 0.0f;
    #pragma unroll
    for (int m = 0; m < 4; ++m)
        #pragma unroll
        for (int q = 0; q < 4; ++q) U = fmaxf(U, a[m][q]);
    int R = (int)sqrtf(U) + 1;       // +1 guards fp rounding; values are exact ints
    R = min(R, 255);
    #pragma unroll
    for (int off = 1; off < 64; off <<= 1) R = max(R, __shfl_xor(R, off));

    for (int kk = 3; kk <= R; ++kk) {                // wave-uniform, no divergence
        float s = (float)(kk * kk);
        #pragma unroll
        for (int q = 0; q < 4; ++q) {
            int kl = max(j0 + (q << 6) - kk, 0);
            int kr = min(j0 + (q << 6) + kk, 255);
            float4 gl = sg2[r][kl];
            float4 gr = sg2[r][kr];
            a[0][q] = fminf(a[0][q], fminf(gl.x, gr.x) + s);
            a[1][q] = fminf(a[1][q], fminf(gl.y, gr.y) + s);
            a[2][q] = fminf(a[2][q], fminf(gl.z, gr.z) + s);
            a[3][q] = fminf(a[3][q], fminf(gl.w, gr.w) + s);
        }
    }

    // weight by (t - sigmoid(x))^2 and reduce
    int rowbase = b * IMG + ((r0 + r) << 8);
    float v = 0.0f;
    #pragma unroll
    for (int q = 0; q < 4; ++q) {
        int j = j0 + (q << 6);
        float dist = (a[0][q] + a[1][q]) + (a[2][q] + a[3][q]);
        float x  = inp[rowbase + j];
        float tt = (float)tgt[rowbase + j];
        float p  = 1.0f / (1.0f + __expf(-x));
        float e  = tt - p;
        v = fmaf(e * e, dist, v);
    }

    #pragma unroll
    for (int off = 32; off > 0; off >>= 1) v += __shfl_down(v, off);
    if ((t & 63) == 0) wsum[t >> 6] = v;
    __syncthreads();
    if (t == 0) {
        float s = (wsum[0] + wsum[1]) + (wsum[2] + wsum[3]);
        atomicAdd(out, s * (1.0f / 524288.0f));   // / (B*H*W)
    }
}

extern "C" void kernel_launch(void* const* d_in, const int* in_sizes, int n_in,
                              void* d_out, int out_size, void* d_ws, size_t ws_size,
                              hipStream_t stream) {
    const float* inp = (const float*)d_in[0];
    const int*   tgt = (const int*)d_in[1];
    unsigned char* PM = (unsigned char*)d_ws;              // 128 KiB
    const unsigned long long* BM = (const unsigned long long*)d_ws;
    float* out = (float*)d_out;

    void* args[] = {(void*)&inp, (void*)&tgt, (void*)&PM, (void*)&BM, (void*)&out};
    hipLaunchCooperativeKernel((const void*)hddt_fused, dim3(512), dim3(256),
                               args, 0, stream);
}

// Round 2
// 86.450 us; speedup vs baseline: 2.0983x; 2.0983x over previous
//
#include <hip/hip_runtime.h>

// HDDTBinaryLoss: loss = mean((t - sigmoid(x))^2 * dist), dist = sum of 4
// exact squared EDTs (p>0.5, ~p, t>0.5, ~t), B=8, C=1, H=W=256.
//
// Round 5 structure (revert of R4 cooperative fusion -- grid.sync cost 120us):
//  K1 build_masks (512 blocks): column occupancy bitmasks as 8-bit partials.
//     PM u8[ ((((src*8+b)*4+wd)*256 + w)*4 + q)*2 + half ] -- little-endian,
//     so the 8 partials alias to the same u64 word (bit h = row wd*64+h,
//     col w) the envelope reads. 128 KiB of d_ws. (Bit-exact verified R4.)
//  K2 envelope (2048 blocks, block = (b, row)): 8 waves/SIMD occupancy,
//     per-thread staging = 4 g2_from_words (was 16 at 512 blocks in R3).
//     - stage g2[k][4 masks] in LDS from bitmasks (clz/ffs 1-D EDT,
//       sentinels reproduce ref BIG=512 carry exactly; absmax 0.0 R2-R4).
//     - EXACT adaptive envelope: dt2[j] = min_k (j-k)^2 + g2[k]. Window
//       |kk|<=2 (includes kk=0 => own-column g2, a hard upper bound U), then
//       R = floor(sqrt(U))+1 wave-maxed -> uniform loop kk=3..R. Pruned kk
//       have kk^2 >= U so they provably cannot improve the min -> exact for
//       ANY input; random 50/50 masks give R ~ 3-6.
//     - weight by (t-p)^2, block-reduce, one atomicAdd per block.

#define IMG 65536

// Squared 1-D column EDT at row i from the mask's ZERO-set bits (z word w
// covers rows 64w..64w+63; bit set = pixel is False for the mask).
__device__ __forceinline__ float g2_from_words(unsigned long long z0,
                                               unsigned long long z1,
                                               unsigned long long z2,
                                               unsigned long long z3,
                                               int i) {
    int wi = i >> 6, bi = i & 63;
    unsigned long long lowm  = (~0ULL) >> (63 - bi);  // bits 0..bi
    unsigned long long highm = (~0ULL) << bi;         // bits bi..63
    unsigned long long z[4] = {z0, z1, z2, z3};

    int lz = -513;  // no zero above => fwd = i + 513  (ref: BIG + i + 1)
    #pragma unroll
    for (int w = 0; w < 4; ++w) {
        unsigned long long m = z[w];
        if (w == wi) m &= lowm;
        if (w >  wi) m = 0;
        if (m) lz = (w << 6) + 63 - __clzll(m);
    }
    int fz = 768;   // no zero below => bwd = 768 - i  (ref: BIG + (255-i) + 1)
    #pragma unroll
    for (int w = 3; w >= 0; --w) {
        unsigned long long m = z[w];
        if (w == wi) m &= highm;
        if (w <  wi) m = 0;
        if (m) fz = (w << 6) + (__ffsll(m) - 1);
    }
    int u = i - lz, d = fz - i;
    float g = (float)(u < d ? u : d);
    return g * g;
}

__global__ __launch_bounds__(256) void build_masks(const float* __restrict__ inp,
                                                   const int* __restrict__ tgt,
                                                   unsigned char* __restrict__ PM,
                                                   float* __restrict__ out) {
    int bid = blockIdx.x;   // 512 blocks
    int w   = threadIdx.x;  // column
    if (bid == 0 && w == 0) out[0] = 0.0f;   // d_out is poisoned before every replay

    int task = bid >> 1;    // 256 tasks: src=task>>7, b=(task>>4)&7, wd=(task>>2)&3, q=task&3
    int half = bid & 1;     // low/high 8 rows of the 16-row q-window
    int src  = task >> 7;
    int b    = (task >> 4) & 7;
    int wd   = (task >> 2) & 3;
    int q    = task & 3;
    int h0   = (wd << 6) + (q << 4) + (half << 3);
    int base = b * IMG + (h0 << 8) + w;

    unsigned int word = 0;
    if (src == 0) {
        #pragma unroll
        for (int hh = 0; hh < 8; ++hh)           // sigmoid(x)>0.5 <=> x>0
            word |= ((unsigned int)(inp[base + (hh << 8)] > 0.0f)) << hh;
    } else {
        #pragma unroll
        for (int hh = 0; hh < 8; ++hh)
            word |= ((unsigned int)(tgt[base + (hh << 8)] > 0)) << hh;
    }
    // byte (q*2+half) of the u64 word for (src,b,wd,w): bit h = row wd*64+q*16+half*8+hh
    PM[(((((size_t)src * 8 + b) * 4 + wd) * 256 + w) * 4 + q) * 2 + half] =
        (unsigned char)word;
}

__global__ __launch_bounds__(256) void envelope(const float* __restrict__ inp,
                                                const int* __restrict__ tgt,
                                                const unsigned long long* __restrict__ BM,
                                                float* __restrict__ out) {
    __shared__ float4 sg2[256];      // [k] = g2 of 4 masks for this row
    __shared__ float wsum[4];

    int b = blockIdx.x >> 8;         // 2048 blocks: 8 b x 256 rows
    int i = blockIdx.x & 255;        // row
    int t = threadIdx.x;             // column

    // ---- stage g2 from bitmasks: thread t = column t, this row only ----
    {
        unsigned long long bp[4], bt[4];
        #pragma unroll
        for (int wd = 0; wd < 4; ++wd) {
            bp[wd] = BM[(((size_t)0 * 8 + b) * 4 + wd) * 256 + t];
            bt[wd] = BM[(((size_t)1 * 8 + b) * 4 + wd) * 256 + t];
        }
        float g0 = g2_from_words(~bp[0], ~bp[1], ~bp[2], ~bp[3], i); // p-mask
        float g1 = g2_from_words( bp[0],  bp[1],  bp[2],  bp[3], i); // ~p
        float g2 = g2_from_words(~bt[0], ~bt[1], ~bt[2], ~bt[3], i); // t-mask
        float g3 = g2_from_words( bt[0],  bt[1],  bt[2],  bt[3], i); // ~t
        sg2[t] = make_float4(g0, g1, g2, g3);
    }
    __syncthreads();

    // ---- adaptive exact lower envelope: thread t = column j = t ----
    float a[4];
    #pragma unroll
    for (int m = 0; m < 4; ++m) a[m] = 1e30f;

    // window |kk| <= 2 (includes kk=0: own-column g2 -> hard upper bound)
    #pragma unroll
    for (int kk = -2; kk <= 2; ++kk) {
        float s = (float)(kk * kk);
        int k = min(max(t + kk, 0), 255);            // clamped k is a valid candidate
        float4 g = sg2[k];                           // stride-1 ds_read_b128
        a[0] = fminf(a[0], g.x + s);
        a[1] = fminf(a[1], g.y + s);
        a[2] = fminf(a[2], g.z + s);
        a[3] = fminf(a[3], g.w + s);
    }

    // prune radius: kk^2 >= U can't improve any entry of this lane
    float U = fmaxf(fmaxf(a[0], a[1]), fmaxf(a[2], a[3]));
    int R = (int)sqrtf(U) + 1;       // +1 guards fp rounding; values are exact ints
    R = min(R, 255);
    #pragma unroll
    for (int off = 1; off < 64; off <<= 1) R = max(R, __shfl_xor(R, off));

    for (int kk = 3; kk <= R; ++kk) {                // wave-uniform, no divergence
        float s = (float)(kk * kk);
        int kl = max(t - kk, 0);
        int kr = min(t + kk, 255);
        float4 gl = sg2[kl];
        float4 gr = sg2[kr];
        a[0] = fminf(a[0], fminf(gl.x, gr.x) + s);
        a[1] = fminf(a[1], fminf(gl.y, gr.y) + s);
        a[2] = fminf(a[2], fminf(gl.z, gr.z) + s);
        a[3] = fminf(a[3], fminf(gl.w, gr.w) + s);
    }

    // ---- weight by (t - sigmoid(x))^2 and reduce ----
    float dist = (a[0] + a[1]) + (a[2] + a[3]);
    float x  = inp[b * IMG + (i << 8) + t];
    float tt = (float)tgt[b * IMG + (i << 8) + t];
    float p  = 1.0f / (1.0f + __expf(-x));
    float e  = tt - p;
    float v  = e * e * dist;

    #pragma unroll
    for (int off = 32; off > 0; off >>= 1) v += __shfl_down(v, off);
    if ((t & 63) == 0) wsum[t >> 6] = v;
    __syncthreads();
    if (t == 0) {
        float s = (wsum[0] + wsum[1]) + (wsum[2] + wsum[3]);
        atomicAdd(out, s * (1.0f / 524288.0f));   // / (B*H*W)
    }
}

extern "C" void kernel_launch(void* const* d_in, const int* in_sizes, int n_in,
                              void* d_out, int out_size, void* d_ws, size_t ws_size,
                              hipStream_t stream) {
    const float* inp = (const float*)d_in[0];
    const int*   tgt = (const int*)d_in[1];
    unsigned char* PM = (unsigned char*)d_ws;              // 128 KiB
    const unsigned long long* BM = (const unsigned long long*)d_ws;
    float* out = (float*)d_out;

    build_masks<<<512, 256, 0, stream>>>(inp, tgt, PM, out);
    envelope<<<2048, 256, 0, stream>>>(inp, tgt, BM, out);
}

// Round 3
// 66.359 us; speedup vs baseline: 2.7335x; 1.3027x over previous
//
#include <hip/hip_runtime.h>

// HDDTBinaryLoss: loss = mean((t - sigmoid(x))^2 * dist), dist = sum of 4
// exact squared EDTs (p>0.5, ~p, t>0.5, ~t), B=8, C=1, H=W=256.
//
// Round 6 structure (revert to R3's proven 512-block tiles; R5's 2048-block
// split cost +18us in per-block overhead/atomics):
//  K1 build_masks (512 blocks): column occupancy bitmasks as 8-bit partials.
//     PM u8[ ((((src*8+b)*4+wd)*256 + w)*4 + q)*2 + half ] -- little-endian,
//     so the 8 partials alias to the same u64 word (bit h = row wd*64+h,
//     col w) the envelope reads. 128 KiB of d_ws. (Bit-exact R4/R5.)
//  K2 envelope (512 blocks, block = (b, 4-row tile)):
//     - NEW: incremental 4-row 1-D EDT staging. The 4-aligned row tile never
//       crosses a u64 word boundary, and nearest-zero distances obey the
//       ref's scan recurrence u(i+1)=bit?0:u(i)+1 (and d downward), so per
//       mask we do 2 full clz/ffs searches (rows r0, r0+3) + 6 cndmask
//       increments instead of 4 full g2_from_words -- ~2.6x less staging
//       VALU, bit-identical results (integers <= 768, exact in fp32).
//     - EXACT adaptive envelope (unchanged from R3): dt2[j] = min_k (j-k)^2
//       + g2[k]; window |kk|<=2 gives hard upper bound U, R=floor(sqrt(U))+1
//       wave-maxed -> uniform loop kk=3..R; pruned kk have kk^2 >= U so they
//       provably cannot improve the min -> exact for ANY input. Random 50/50
//       masks give R ~ 3-6.
//     - weight by (t-p)^2, block-reduce, one atomicAdd per block (512 total;
//       2048 was a regression).

#define IMG 65536

// last zero position <= i (bit set in z = zero pixel of the mask), or -513
// if none (reproduces ref fwd carry BIG=512: u = i+513).
__device__ __forceinline__ int last_zero_le(unsigned long long z0,
                                            unsigned long long z1,
                                            unsigned long long z2,
                                            unsigned long long z3,
                                            int i) {
    int wi = i >> 6, bi = i & 63;
    unsigned long long lowm = (~0ULL) >> (63 - bi);  // bits 0..bi
    unsigned long long z[4] = {z0, z1, z2, z3};
    int lz = -513;
    #pragma unroll
    for (int w = 0; w < 4; ++w) {
        unsigned long long m = z[w];
        if (w == wi) m &= lowm;
        if (w >  wi) m = 0;
        if (m) lz = (w << 6) + 63 - __clzll(m);
    }
    return lz;
}

// first zero position >= i, or 768 if none (ref bwd carry: d = 768-i).
__device__ __forceinline__ int first_zero_ge(unsigned long long z0,
                                             unsigned long long z1,
                                             unsigned long long z2,
                                             unsigned long long z3,
                                             int i) {
    int wi = i >> 6, bi = i & 63;
    unsigned long long highm = (~0ULL) << bi;        // bits bi..63
    unsigned long long z[4] = {z0, z1, z2, z3};
    int fz = 768;
    #pragma unroll
    for (int w = 3; w >= 0; --w) {
        unsigned long long m = z[w];
        if (w == wi) m &= highm;
        if (w <  wi) m = 0;
        if (m) fz = (w << 6) + (__ffsll(m) - 1);
    }
    return fz;
}

// Squared 1-D column EDT for the 4-aligned row tile i0..i0+3 (all in one u64
// word since i0%64 <= 60). 2 full searches + incremental chains -- exactly
// the reference scan recurrence, so bit-identical to per-row full searches.
__device__ __forceinline__ void g2_tile4(unsigned long long z0,
                                         unsigned long long z1,
                                         unsigned long long z2,
                                         unsigned long long z3,
                                         int i0, float g2out[4]) {
    int lz = last_zero_le(z0, z1, z2, z3, i0);
    int fz = first_zero_ge(z0, z1, z2, z3, i0 + 3);

    int wi = i0 >> 6, bi = i0 & 63;                  // wi is block-uniform
    unsigned long long zw = z0;
    if (wi == 1) zw = z1;
    if (wi == 2) zw = z2;
    if (wi == 3) zw = z3;
    unsigned int nib = (unsigned int)(zw >> bi) & 15u;  // zero flags rows i0..i0+3

    int u0 = i0 - lz;                                // row i0 (search includes i0)
    int d3 = fz - (i0 + 3);                          // row i0+3
    int u_0 = u0;                                    // bit0 set => lz==i0 => u0==0
    int u_1 = (nib & 2u) ? 0 : u_0 + 1;
    int u_2 = (nib & 4u) ? 0 : u_1 + 1;
    int u_3 = (nib & 8u) ? 0 : u_2 + 1;
    int d_3 = d3;                                    // bit3 set => fz==i0+3 => d3==0
    int d_2 = (nib & 4u) ? 0 : d_3 + 1;
    int d_1 = (nib & 2u) ? 0 : d_2 + 1;
    int d_0 = (nib & 1u) ? 0 : d_1 + 1;

    float g0 = (float)min(u_0, d_0);
    float g1 = (float)min(u_1, d_1);
    float g2 = (float)min(u_2, d_2);
    float g3 = (float)min(u_3, d_3);
    g2out[0] = g0 * g0;
    g2out[1] = g1 * g1;
    g2out[2] = g2 * g2;
    g2out[3] = g3 * g3;
}

__global__ __launch_bounds__(256) void build_masks(const float* __restrict__ inp,
                                                   const int* __restrict__ tgt,
                                                   unsigned char* __restrict__ PM,
                                                   float* __restrict__ out) {
    int bid = blockIdx.x;   // 512 blocks
    int w   = threadIdx.x;  // column
    if (bid == 0 && w == 0) out[0] = 0.0f;   // d_out is poisoned before every replay

    int task = bid >> 1;    // 256 tasks: src=task>>7, b=(task>>4)&7, wd=(task>>2)&3, q=task&3
    int half = bid & 1;     // low/high 8 rows of the 16-row q-window
    int src  = task >> 7;
    int b    = (task >> 4) & 7;
    int wd   = (task >> 2) & 3;
    int q    = task & 3;
    int h0   = (wd << 6) + (q << 4) + (half << 3);
    int base = b * IMG + (h0 << 8) + w;

    unsigned int word = 0;
    if (src == 0) {
        #pragma unroll
        for (int hh = 0; hh < 8; ++hh)           // sigmoid(x)>0.5 <=> x>0
            word |= ((unsigned int)(inp[base + (hh << 8)] > 0.0f)) << hh;
    } else {
        #pragma unroll
        for (int hh = 0; hh < 8; ++hh)
            word |= ((unsigned int)(tgt[base + (hh << 8)] > 0)) << hh;
    }
    // byte (q*2+half) of the u64 word for (src,b,wd,w): bit h = row wd*64+q*16+half*8+hh
    PM[(((((size_t)src * 8 + b) * 4 + wd) * 256 + w) * 4 + q) * 2 + half] =
        (unsigned char)word;
}

__global__ __launch_bounds__(256) void envelope(const float* __restrict__ inp,
                                                const int* __restrict__ tgt,
                                                const unsigned long long* __restrict__ BM,
                                                float* __restrict__ out) {
    __shared__ float4 sg2[4][256];   // [row in tile][k] = g2 of 4 masks
    __shared__ float wsum[4];

    int b  = blockIdx.x >> 6;        // 512 blocks: 8 b x 64 row-tiles
    int r0 = (blockIdx.x & 63) << 2;
    int t  = threadIdx.x;

    // ---- stage g2 from bitmasks: thread t = column t, 4 rows, 4 masks ----
    {
        unsigned long long bp[4], bt[4];
        #pragma unroll
        for (int wd = 0; wd < 4; ++wd) {
            bp[wd] = BM[(((size_t)0 * 8 + b) * 4 + wd) * 256 + t];
            bt[wd] = BM[(((size_t)1 * 8 + b) * 4 + wd) * 256 + t];
        }
        float gp[4], gnp[4], gt[4], gnt[4];
        g2_tile4(~bp[0], ~bp[1], ~bp[2], ~bp[3], r0, gp);   // p-mask
        g2_tile4( bp[0],  bp[1],  bp[2],  bp[3], r0, gnp);  // ~p
        g2_tile4(~bt[0], ~bt[1], ~bt[2], ~bt[3], r0, gt);   // t-mask
        g2_tile4( bt[0],  bt[1],  bt[2],  bt[3], r0, gnt);  // ~t
        #pragma unroll
        for (int rr = 0; rr < 4; ++rr)
            sg2[rr][t] = make_float4(gp[rr], gnp[rr], gt[rr], gnt[rr]);
    }
    __syncthreads();

    // ---- adaptive exact lower envelope: wave r = row r0+r, lane j0, 4 pixels ----
    int r  = t >> 6;
    int j0 = t & 63;
    float a[4][4];                   // [mask][q]
    #pragma unroll
    for (int m = 0; m < 4; ++m)
        #pragma unroll
        for (int q = 0; q < 4; ++q) a[m][q] = 1e30f;

    // window |kk| <= 2 (includes kk=0: own-column g2 -> hard upper bound)
    #pragma unroll
    for (int kk = -2; kk <= 2; ++kk) {
        float s = (float)(kk * kk);
        #pragma unroll
        for (int q = 0; q < 4; ++q) {
            int k = j0 + (q << 6) + kk;
            k = min(max(k, 0), 255);                 // clamped k is a valid candidate
            float4 g = sg2[r][k];                    // stride-1 ds_read_b128
            a[0][q] = fminf(a[0][q], g.x + s);
            a[1][q] = fminf(a[1][q], g.y + s);
            a[2][q] = fminf(a[2][q], g.z + s);
            a[3][q] = fminf(a[3][q], g.w + s);
        }
    }

    // prune radius: kk^2 >= U can't improve any entry of this lane
    float U = 0.0f;
    #pragma unroll
    for (int m = 0; m < 4; ++m)
        #pragma unroll
        for (int q = 0; q < 4; ++q) U = fmaxf(U, a[m][q]);
    int R = (int)sqrtf(U) + 1;       // +1 guards fp rounding; values are exact ints
    R = min(R, 255);
    #pragma unroll
    for (int off = 1; off < 64; off <<= 1) R = max(R, __shfl_xor(R, off));

    for (int kk = 3; kk <= R; ++kk) {                // wave-uniform, no divergence
        float s = (float)(kk * kk);
        #pragma unroll
        for (int q = 0; q < 4; ++q) {
            int kl = max(j0 + (q << 6) - kk, 0);
            int kr = min(j0 + (q << 6) + kk, 255);
            float4 gl = sg2[r][kl];
            float4 gr = sg2[r][kr];
            a[0][q] = fminf(a[0][q], fminf(gl.x, gr.x) + s);
            a[1][q] = fminf(a[1][q], fminf(gl.y, gr.y) + s);
            a[2][q] = fminf(a[2][q], fminf(gl.z, gr.z) + s);
            a[3][q] = fminf(a[3][q], fminf(gl.w, gr.w) + s);
        }
    }

    // ---- weight by (t - sigmoid(x))^2 and reduce ----
    int rowbase = b * IMG + ((r0 + r) << 8);
    float v = 0.0f;
    #pragma unroll
    for (int q = 0; q < 4; ++q) {
        int j = j0 + (q << 6);
        float dist = (a[0][q] + a[1][q]) + (a[2][q] + a[3][q]);
        float x  = inp[rowbase + j];
        float tt = (float)tgt[rowbase + j];
        float p  = 1.0f / (1.0f + __expf(-x));
        float e  = tt - p;
        v = fmaf(e * e, dist, v);
    }

    #pragma unroll
    for (int off = 32; off > 0; off >>= 1) v += __shfl_down(v, off);
    if ((t & 63) == 0) wsum[t >> 6] = v;
    __syncthreads();
    if (t == 0) {
        float s = (wsum[0] + wsum[1]) + (wsum[2] + wsum[3]);
        atomicAdd(out, s * (1.0f / 524288.0f));   // / (B*H*W)
    }
}

extern "C" void kernel_launch(void* const* d_in, const int* in_sizes, int n_in,
                              void* d_out, int out_size, void* d_ws, size_t ws_size,
                              hipStream_t stream) {
    const float* inp = (const float*)d_in[0];
    const int*   tgt = (const int*)d_in[1];
    unsigned char* PM = (unsigned char*)d_ws;              // 128 KiB
    const unsigned long long* BM = (const unsigned long long*)d_ws;
    float* out = (float*)d_out;

    build_masks<<<512, 256, 0, stream>>>(inp, tgt, PM, out);
    envelope<<<512, 256, 0, stream>>>(inp, tgt, BM, out);
}